// Round 1
// baseline (2473.244 us; speedup 1.0000x reference)
//
#include <hip/hip_runtime.h>

// ---------------------------------------------------------------------------
// HardConstrainedMLP: 3-layer MLP -> 100 relaxed DR iterations -> P_eq(P_box)
// Key identity: with AAT = A A^T + 1e-6 I = L L^T  (Cholesky),
//   G  = L^{-1} A          (64 x 256)
//   b' = L^{-1} b_row      (per row, 64)
//   corr(w) = ((w@A^T - b)@AAT^{-1})@A = (w@G^T - b')@G
// Iteration: p = clip(z); w = 2p - z; z += omega*(p - z - corr(w))
// Output:    p = clip(z); out = p - corr_with_w_equal_p
// ---------------------------------------------------------------------------

__device__ __forceinline__ int swz(int row, int d) {
  // XOR-swizzled element index into a [64][256] LDS tile (granule = 4 floats)
  return (row << 8) | ((((d >> 2) ^ (row & 7)) << 2) | (d & 3));
}

// ---------------- P1: AAT, Cholesky L, G = L^{-1} A ------------------------
__global__ __launch_bounds__(256) void prep_kernel(const float* __restrict__ A,
                                                   float* __restrict__ G_out,
                                                   float* __restrict__ L_out) {
  __shared__ float As[64 * 257];
  __shared__ float T[64 * 65];      // AAT -> L (lower)
  __shared__ float gcol[64 * 256];  // g[i] for column t at gcol[i*256+t]
  const int t = threadIdx.x;

  for (int q = 0; q < 64; ++q) {
    int f = t + 256 * q;
    int m = f >> 8, d = f & 255;
    As[m * 257 + d] = A[f];
  }
  __syncthreads();

  for (int q = 0; q < 16; ++q) {
    int f = t + 256 * q;
    int i = f >> 6, j = f & 63;
    float s = 0.f;
    for (int d = 0; d < 256; ++d) s += As[i * 257 + d] * As[j * 257 + d];
    if (i == j) s += 1e-6f;
    T[i * 65 + j] = s;
  }
  __syncthreads();

  // right-looking Cholesky (lower triangle of T)
  for (int j = 0; j < 64; ++j) {
    if (t == 0) T[j * 65 + j] = sqrtf(T[j * 65 + j]);
    __syncthreads();
    float dj = T[j * 65 + j];
    if (t > j && t < 64) T[t * 65 + j] /= dj;
    __syncthreads();
    for (int i = j + 1 + (t >> 4); i < 64; i += 16)
      for (int k = j + 1 + (t & 15); k <= i; k += 16)
        T[i * 65 + k] -= T[i * 65 + j] * T[k * 65 + j];
    __syncthreads();
  }

  for (int q = 0; q < 16; ++q) {
    int f = t + 256 * q;
    int i = f >> 6, j = f & 63;
    L_out[f] = (j <= i) ? T[i * 65 + j] : 0.f;
  }

  // forward solve L g = A[:, t]  (one column per thread)
  for (int i = 0; i < 64; ++i) {
    float s = As[i * 257 + t];
    for (int j = 0; j < i; ++j) s -= T[i * 65 + j] * gcol[j * 256 + t];
    gcol[i * 256 + t] = s / T[i * 65 + i];
  }
  for (int i = 0; i < 64; ++i) G_out[i * 256 + t] = gcol[i * 256 + t];
}

// ---------------- P2: b'[row] = L^{-1} b[row] ------------------------------
__global__ __launch_bounds__(256) void bprime_kernel(const float* __restrict__ bg,
                                                     const float* __restrict__ L,
                                                     float* __restrict__ bp) {
  __shared__ float Ls[64 * 64];
  __shared__ float xl[64 * 256];  // x[i] for thread t at xl[i*256+t]
  const int t = threadIdx.x;
  for (int q = 0; q < 16; ++q) Ls[t + 256 * q] = L[t + 256 * q];
  __syncthreads();
  const int row = blockIdx.x * 256 + t;
  for (int i = 0; i < 64; ++i) {
    float s = bg[row * 64 + i];
    for (int j = 0; j < i; ++j) s -= Ls[i * 64 + j] * xl[j * 256 + t];
    float x = s / Ls[i * 64 + i];
    xl[i * 256 + t] = x;
    bp[row * 64 + i] = x;
  }
}

// ---------------- MLP: generic tiled SGEMM + bias + optional relu ----------
__global__ __launch_bounds__(256) void gemm_kernel(const float* __restrict__ X,
                                                   const float* __restrict__ W,
                                                   const float* __restrict__ bias,
                                                   float* __restrict__ Y,
                                                   int Mdim, int Ndim, int Kdim,
                                                   int relu) {
  __shared__ float Xs[16][65];
  __shared__ float Ws[16][68];
  const int t = threadIdx.x;
  const int row0 = blockIdx.x * 64, n0 = blockIdx.y * 64;
  const int ty = t >> 4, tx = t & 15;
  float acc[4][4] = {};
  const int nk = (Kdim + 15) / 16;
  for (int kc = 0; kc < nk; ++kc) {
    const int k0 = kc * 16;
    {
      int c = t & 15, r0 = t >> 4;
      for (int p = 0; p < 4; ++p) {
        int r = r0 + 16 * p;
        float v = 0.f;
        if (k0 + c < Kdim) v = X[(size_t)(row0 + r) * Kdim + k0 + c];
        Xs[c][r] = v;
      }
      int c2 = t & 63, r2 = t >> 6;
      for (int p = 0; p < 4; ++p) {
        int r = r2 + 4 * p;
        float v = 0.f;
        if (k0 + r < Kdim && n0 + c2 < Ndim) v = W[(size_t)(k0 + r) * Ndim + n0 + c2];
        Ws[r][c2] = v;
      }
    }
    __syncthreads();
#pragma unroll
    for (int k = 0; k < 16; ++k) {
      float a[4], bw[4];
#pragma unroll
      for (int ii = 0; ii < 4; ++ii) a[ii] = Xs[k][ty * 4 + ii];
#pragma unroll
      for (int jj = 0; jj < 4; ++jj) bw[jj] = Ws[k][tx * 4 + jj];
#pragma unroll
      for (int ii = 0; ii < 4; ++ii)
#pragma unroll
        for (int jj = 0; jj < 4; ++jj) acc[ii][jj] += a[ii] * bw[jj];
    }
    __syncthreads();
  }
  for (int ii = 0; ii < 4; ++ii) {
    int row = row0 + ty * 4 + ii;
    for (int jj = 0; jj < 4; ++jj) {
      int col = n0 + tx * 4 + jj;
      if (col < Ndim) {
        float v = acc[ii][jj] + bias[col];
        if (relu) v = fmaxf(v, 0.f);
        Y[(size_t)row * Ndim + col] = v;
      }
    }
  }
}

// ---------------- ITER: fused 100x DR + final projection -------------------
// 256 blocks (1/CU), 64 rows/block, z resident in registers (8x8 per thread).
__global__ __launch_bounds__(256, 1) void iter_kernel(const float* __restrict__ y0,
                                                      const float* __restrict__ Gg,
                                                      const float* __restrict__ bpg,
                                                      const float* __restrict__ lb,
                                                      const float* __restrict__ ub,
                                                      const int* __restrict__ n_iter_p,
                                                      float* __restrict__ out) {
  __shared__ float Gs[16384];   // [64][256] swizzled
  __shared__ float ws_[16384];  // w (swizzled); reused for MV1 partials [2][64][68]
  __shared__ float rs[64 * 68]; // r = w@G^T - b'
  const int t = threadIdx.x;
  const int row_base = blockIdx.x * 64;
  const int n_iter = n_iter_p[0];

  // load G (swizzled)
  for (int q = 0; q < 64; ++q) {
    int f = t + 256 * q;
    Gs[swz(f >> 8, f & 255)] = Gg[f];
  }

  // z tile: rows a+8i, cols 8e+j
  const int a = t >> 5, e = t & 31;
  float z[8][8], lbr[8], ubr[8];
  {
    float4 l0 = *(const float4*)&lb[8 * e];
    float4 l1 = *(const float4*)&lb[8 * e + 4];
    float4 u0 = *(const float4*)&ub[8 * e];
    float4 u1 = *(const float4*)&ub[8 * e + 4];
    lbr[0] = l0.x; lbr[1] = l0.y; lbr[2] = l0.z; lbr[3] = l0.w;
    lbr[4] = l1.x; lbr[5] = l1.y; lbr[6] = l1.z; lbr[7] = l1.w;
    ubr[0] = u0.x; ubr[1] = u0.y; ubr[2] = u0.z; ubr[3] = u0.w;
    ubr[4] = u1.x; ubr[5] = u1.y; ubr[6] = u1.z; ubr[7] = u1.w;
  }
#pragma unroll
  for (int i = 0; i < 8; ++i) {
    int row = row_base + a + 8 * i;
    float4 v0 = *(const float4*)&y0[row * 256 + 8 * e];
    float4 v1 = *(const float4*)&y0[row * 256 + 8 * e + 4];
    z[i][0] = v0.x; z[i][1] = v0.y; z[i][2] = v0.z; z[i][3] = v0.w;
    z[i][4] = v1.x; z[i][5] = v1.y; z[i][6] = v1.z; z[i][7] = v1.w;
  }
  // b' registers matching the reduce-phase slice: row t>>2, m = 16*(t&3)+q
  float bpr[16];
  {
    const int rr = row_base + (t >> 2);
    const int mb = 16 * (t & 3);
#pragma unroll
    for (int q4 = 0; q4 < 4; ++q4) {
      float4 v = *(const float4*)&bpg[rr * 64 + mb + 4 * q4];
      bpr[4 * q4 + 0] = v.x; bpr[4 * q4 + 1] = v.y;
      bpr[4 * q4 + 2] = v.z; bpr[4 * q4 + 3] = v.w;
    }
  }

  // MV1 mapping: wave -> (k-half, row-half); lane -> (m-group, row-group)
  const int lane = t & 63, wv = t >> 6;
  const int kg = wv & 1, rh = wv >> 1;
  const int mg = lane & 7, rr1 = lane >> 3;

  __syncthreads();  // Gs ready

  for (int it = 0; it <= n_iter; ++it) {
    const bool last = (it == n_iter);

    // ---- phase W: w = 2*clip(z)-z (or p on final pass), swizzled store ----
#pragma unroll
    for (int i = 0; i < 8; ++i) {
      int row = a + 8 * i;
      float wq[8];
#pragma unroll
      for (int j = 0; j < 8; ++j) {
        float p = fminf(fmaxf(z[i][j], lbr[j]), ubr[j]);
        wq[j] = last ? p : (2.f * p - z[i][j]);
      }
      *(float4*)&ws_[swz(row, 8 * e)] = make_float4(wq[0], wq[1], wq[2], wq[3]);
      *(float4*)&ws_[swz(row, 8 * e + 4)] = make_float4(wq[4], wq[5], wq[6], wq[7]);
    }
    __syncthreads();

    // ---- MV1: r_partial = w @ G^T over this wave's k-half ----
    float acc1[4][8] = {};
#pragma unroll 2
    for (int kk = 0; kk < 32; ++kk) {
      const int k = kg * 128 + kk * 4;
      float4 wv4[4], gv4[8];
#pragma unroll
      for (int i = 0; i < 4; ++i) {
        int row = rh * 32 + rr1 + 8 * i;
        wv4[i] = *(const float4*)&ws_[swz(row, k)];
      }
#pragma unroll
      for (int jm = 0; jm < 8; ++jm) {
        int m = mg + 8 * jm;
        gv4[jm] = *(const float4*)&Gs[swz(m, k)];
      }
#pragma unroll
      for (int i = 0; i < 4; ++i)
#pragma unroll
        for (int jm = 0; jm < 8; ++jm)
          acc1[i][jm] += wv4[i].x * gv4[jm].x + wv4[i].y * gv4[jm].y +
                         wv4[i].z * gv4[jm].z + wv4[i].w * gv4[jm].w;
    }
    __syncthreads();  // all w reads done -> ws_ reusable for partials

    float* part = &ws_[0];  // [2][64][68]
#pragma unroll
    for (int i = 0; i < 4; ++i) {
      int row = rh * 32 + rr1 + 8 * i;
#pragma unroll
      for (int jm = 0; jm < 8; ++jm) part[kg * 4352 + row * 68 + (mg + 8 * jm)] = acc1[i][jm];
    }
    __syncthreads();

    // ---- reduce partials, subtract b' ----
    {
      const int rr2 = t >> 2;
      const int mb = 16 * (t & 3);
#pragma unroll
      for (int q = 0; q < 16; ++q) {
        int m = mb + q;
        rs[rr2 * 68 + m] = part[rr2 * 68 + m] + part[4352 + rr2 * 68 + m] - bpr[q];
      }
    }
    __syncthreads();

    // ---- MV2: corr = r @ G ----
    float acc2[8][8] = {};
#pragma unroll 2
    for (int kk = 0; kk < 16; ++kk) {
      const int k = kk * 4;
      float4 rv[8];
#pragma unroll
      for (int i = 0; i < 8; ++i) rv[i] = *(const float4*)&rs[(a + 8 * i) * 68 + k];
#pragma unroll
      for (int mm = 0; mm < 4; ++mm) {
        const int m = k + mm;
        float4 g0 = *(const float4*)&Gs[swz(m, 8 * e)];
        float4 g1 = *(const float4*)&Gs[swz(m, 8 * e + 4)];
#pragma unroll
        for (int i = 0; i < 8; ++i) {
          float rvm = (mm == 0) ? rv[i].x : (mm == 1) ? rv[i].y : (mm == 2) ? rv[i].z : rv[i].w;
          acc2[i][0] += rvm * g0.x; acc2[i][1] += rvm * g0.y;
          acc2[i][2] += rvm * g0.z; acc2[i][3] += rvm * g0.w;
          acc2[i][4] += rvm * g1.x; acc2[i][5] += rvm * g1.y;
          acc2[i][6] += rvm * g1.z; acc2[i][7] += rvm * g1.w;
        }
      }
    }

    if (!last) {
      // z += omega * (p - z - corr)
#pragma unroll
      for (int i = 0; i < 8; ++i)
#pragma unroll
        for (int j = 0; j < 8; ++j) {
          float p = fminf(fmaxf(z[i][j], lbr[j]), ubr[j]);
          z[i][j] += 1.7f * (p - z[i][j] - acc2[i][j]);
        }
    } else {
      // out = p - corr(p)
#pragma unroll
      for (int i = 0; i < 8; ++i) {
        int row = row_base + a + 8 * i;
        float o[8];
#pragma unroll
        for (int j = 0; j < 8; ++j) {
          float p = fminf(fmaxf(z[i][j], lbr[j]), ubr[j]);
          o[j] = p - acc2[i][j];
        }
        *(float4*)&out[row * 256 + 8 * e] = make_float4(o[0], o[1], o[2], o[3]);
        *(float4*)&out[row * 256 + 8 * e + 4] = make_float4(o[4], o[5], o[6], o[7]);
      }
    }
  }
}

// ---------------------------------------------------------------------------
extern "C" void kernel_launch(void* const* d_in, const int* in_sizes, int n_in,
                              void* d_out, int out_size, void* d_ws, size_t ws_size,
                              hipStream_t stream) {
  (void)in_sizes; (void)n_in; (void)out_size; (void)ws_size;
  const float* x  = (const float*)d_in[0];
  const float* bM = (const float*)d_in[1];
  const float* W1 = (const float*)d_in[2];
  const float* b1 = (const float*)d_in[3];
  const float* W2 = (const float*)d_in[4];
  const float* b2 = (const float*)d_in[5];
  const float* W3 = (const float*)d_in[6];
  const float* b3 = (const float*)d_in[7];
  const float* A  = (const float*)d_in[8];
  const float* lb = (const float*)d_in[9];
  const float* ub = (const float*)d_in[10];
  const int* n_iter = (const int*)d_in[11];
  float* out = (float*)d_out;

  float* ws = (float*)d_ws;
  float* y  = ws;                       // 16384*256  (region0)
  float* h1 = ws;                       // 16384*200  (overlays y; dead before y is written)
  float* h2 = y + 16384 * 256;          // 16384*200
  float* bp = h2 + 16384 * 200;         // 16384*64
  float* G  = bp + 16384 * 64;          // 64*256
  float* L  = G + 64 * 256;             // 64*64

  hipLaunchKernelGGL(prep_kernel, dim3(1), dim3(256), 0, stream, A, G, L);
  hipLaunchKernelGGL(bprime_kernel, dim3(64), dim3(256), 0, stream, bM, L, bp);
  hipLaunchKernelGGL(gemm_kernel, dim3(256, 4), dim3(256), 0, stream, x,  W1, b1, h1, 16384, 200, 256, 1);
  hipLaunchKernelGGL(gemm_kernel, dim3(256, 4), dim3(256), 0, stream, h1, W2, b2, h2, 16384, 200, 200, 1);
  hipLaunchKernelGGL(gemm_kernel, dim3(256, 4), dim3(256), 0, stream, h2, W3, b3, y,  16384, 256, 200, 0);
  hipLaunchKernelGGL(iter_kernel, dim3(256), dim3(256), 0, stream, y, G, bp, lb, ub, n_iter, out);
}

// Round 2
// 944.578 us; speedup vs baseline: 2.6184x; 2.6184x over previous
//
#include <hip/hip_runtime.h>

// ---------------------------------------------------------------------------
// HardConstrainedMLP: 3-layer MLP -> 100 relaxed DR iterations -> P_eq(P_box)
//   AAT = A A^T + 1e-6 I = L L^T,  G = L^{-1}A (64x256),  b' = L^{-1} b_row
//   corr(w) = (w@G^T - b')@G ;  z += 1.7*(clip(z) - z - corr(2*clip(z)-z))
// R2: DR iterations on MFMA (truncation-split bf16, 3 products ~ fp32 exact).
// ---------------------------------------------------------------------------

typedef float f32x4 __attribute__((ext_vector_type(4)));
typedef short short8 __attribute__((ext_vector_type(8)));

__device__ __forceinline__ unsigned pack_hi(float a, float b) {
  // bf16x2: low half = trunc_bf16(a), high half = trunc_bf16(b)
  return __builtin_amdgcn_perm(__float_as_uint(b), __float_as_uint(a), 0x07060302u);
}
__device__ __forceinline__ short8 mk_short8(unsigned a, unsigned b, unsigned c, unsigned d) {
  union { unsigned u[4]; short8 v; } x;
  x.u[0] = a; x.u[1] = b; x.u[2] = c; x.u[3] = d;
  return x.v;
}
__device__ __forceinline__ void split8(const float* f, short8& hi, short8& lo) {
  float lof[8];
#pragma unroll
  for (int i = 0; i < 8; ++i)
    lof[i] = f[i] - __uint_as_float(__float_as_uint(f[i]) & 0xFFFF0000u);
  hi = mk_short8(pack_hi(f[0], f[1]), pack_hi(f[2], f[3]), pack_hi(f[4], f[5]), pack_hi(f[6], f[7]));
  lo = mk_short8(pack_hi(lof[0], lof[1]), pack_hi(lof[2], lof[3]), pack_hi(lof[4], lof[5]), pack_hi(lof[6], lof[7]));
}
__device__ __forceinline__ f32x4 mfma16(short8 a, short8 b, f32x4 c) {
  return __builtin_amdgcn_mfma_f32_16x16x32_bf16(a, b, c, 0, 0, 0);
}

// ---------------- P1: AAT, Cholesky L, G = L^{-1} A ------------------------
__global__ __launch_bounds__(256) void prep_kernel(const float* __restrict__ A,
                                                   float* __restrict__ G_out,
                                                   float* __restrict__ L_out) {
  __shared__ float As[64 * 257];
  __shared__ float T[64 * 65];
  __shared__ float gcol[64 * 256];
  const int t = threadIdx.x;

  for (int q = 0; q < 64; ++q) {
    int f = t + 256 * q;
    As[(f >> 8) * 257 + (f & 255)] = A[f];
  }
  __syncthreads();

  for (int q = 0; q < 16; ++q) {
    int f = t + 256 * q;
    int i = f >> 6, j = f & 63;
    float s = 0.f;
    for (int d = 0; d < 256; ++d) s += As[i * 257 + d] * As[j * 257 + d];
    if (i == j) s += 1e-6f;
    T[i * 65 + j] = s;
  }
  __syncthreads();

  for (int j = 0; j < 64; ++j) {
    if (t == 0) T[j * 65 + j] = sqrtf(T[j * 65 + j]);
    __syncthreads();
    float dj = T[j * 65 + j];
    if (t > j && t < 64) T[t * 65 + j] /= dj;
    __syncthreads();
    for (int i = j + 1 + (t >> 4); i < 64; i += 16)
      for (int k = j + 1 + (t & 15); k <= i; k += 16)
        T[i * 65 + k] -= T[i * 65 + j] * T[k * 65 + j];
    __syncthreads();
  }

  for (int q = 0; q < 16; ++q) {
    int f = t + 256 * q;
    int i = f >> 6, j = f & 63;
    L_out[f] = (j <= i) ? T[i * 65 + j] : 0.f;
  }

  for (int i = 0; i < 64; ++i) {
    float s = As[i * 257 + t];
    for (int j = 0; j < i; ++j) s -= T[i * 65 + j] * gcol[j * 256 + t];
    gcol[i * 256 + t] = s / T[i * 65 + i];
  }
  for (int i = 0; i < 64; ++i) G_out[i * 256 + t] = gcol[i * 256 + t];
}

// ---------------- P2: b'[row] = L^{-1} b[row] ------------------------------
__global__ __launch_bounds__(256) void bprime_kernel(const float* __restrict__ bg,
                                                     const float* __restrict__ L,
                                                     float* __restrict__ bp) {
  __shared__ float Ls[64 * 64];
  __shared__ float xl[64 * 256];
  const int t = threadIdx.x;
  for (int q = 0; q < 16; ++q) Ls[t + 256 * q] = L[t + 256 * q];
  __syncthreads();
  const int row = blockIdx.x * 256 + t;
  for (int i = 0; i < 64; ++i) {
    float s = bg[row * 64 + i];
    for (int j = 0; j < i; ++j) s -= Ls[i * 64 + j] * xl[j * 256 + t];
    float x = s / Ls[i * 64 + i];
    xl[i * 256 + t] = x;
    bp[row * 64 + i] = x;
  }
}

// ---------------- MLP: generic tiled SGEMM + bias + optional relu ----------
__global__ __launch_bounds__(256) void gemm_kernel(const float* __restrict__ X,
                                                   const float* __restrict__ W,
                                                   const float* __restrict__ bias,
                                                   float* __restrict__ Y,
                                                   int Mdim, int Ndim, int Kdim,
                                                   int relu) {
  __shared__ float Xs[16][65];
  __shared__ float Ws[16][68];
  const int t = threadIdx.x;
  const int row0 = blockIdx.x * 64, n0 = blockIdx.y * 64;
  const int ty = t >> 4, tx = t & 15;
  float acc[4][4] = {};
  const int nk = (Kdim + 15) / 16;
  for (int kc = 0; kc < nk; ++kc) {
    const int k0 = kc * 16;
    {
      int c = t & 15, r0 = t >> 4;
      for (int p = 0; p < 4; ++p) {
        int r = r0 + 16 * p;
        float v = 0.f;
        if (k0 + c < Kdim) v = X[(size_t)(row0 + r) * Kdim + k0 + c];
        Xs[c][r] = v;
      }
      int c2 = t & 63, r2 = t >> 6;
      for (int p = 0; p < 4; ++p) {
        int r = r2 + 4 * p;
        float v = 0.f;
        if (k0 + r < Kdim && n0 + c2 < Ndim) v = W[(size_t)(k0 + r) * Ndim + n0 + c2];
        Ws[r][c2] = v;
      }
    }
    __syncthreads();
#pragma unroll
    for (int k = 0; k < 16; ++k) {
      float a[4], bw[4];
#pragma unroll
      for (int ii = 0; ii < 4; ++ii) a[ii] = Xs[k][ty * 4 + ii];
#pragma unroll
      for (int jj = 0; jj < 4; ++jj) bw[jj] = Ws[k][tx * 4 + jj];
#pragma unroll
      for (int ii = 0; ii < 4; ++ii)
#pragma unroll
        for (int jj = 0; jj < 4; ++jj) acc[ii][jj] += a[ii] * bw[jj];
    }
    __syncthreads();
  }
  for (int ii = 0; ii < 4; ++ii) {
    int row = row0 + ty * 4 + ii;
    for (int jj = 0; jj < 4; ++jj) {
      int col = n0 + tx * 4 + jj;
      if (col < Ndim) {
        float v = acc[ii][jj] + bias[col];
        if (relu) v = fmaxf(v, 0.f);
        Y[(size_t)row * Ndim + col] = v;
      }
    }
  }
}

// ---------------- ITER: fused 100x DR on MFMA ------------------------------
// 256 blocks, 256 threads (4 waves), 64 rows/block. z in registers (C/D
// layout). G fragments (bf16 hi/lo) preloaded in registers, iteration-
// invariant. Per iter: w->LDS(f32,swz); MV1 A=w B=G^T (k-half x row-half per
// wave); reduce partials -> r (bf16 hi/lo, swz); MV2 A=r B=G (n-quarter per
// wave); z update in regs. 3 barriers/iter.
__global__ __launch_bounds__(256, 1) void iter_kernel(const float* __restrict__ y0,
                                                      const float* __restrict__ Gg,
                                                      const float* __restrict__ bpg,
                                                      const float* __restrict__ lb,
                                                      const float* __restrict__ ub,
                                                      const int* __restrict__ n_iter_p,
                                                      float* __restrict__ out) {
  __shared__ __align__(16) float wbuf[64 * 256];      // w, f32, granule-4 XOR swz
  __shared__ __align__(16) float part[2 * 64 * 68];   // MV1 partials [kg][row][68]
  __shared__ __align__(16) unsigned rsh_[64 * 32];    // r hi, bf16x2, swz
  __shared__ __align__(16) unsigned rsl_[64 * 32];    // r lo

  const int t = threadIdx.x, lane = t & 63, wv = t >> 6;
  const int row_base = blockIdx.x * 64;
  const int n_iter = n_iter_p[0];
  const int kg = wv & 1, mh = wv >> 1;
  const int lhi = lane >> 4, llo = lane & 15;

  // ---- G fragments: MV1 B[k][m] = G[m][k] ----
  short8 B1h[4][4], B1l[4][4];
#pragma unroll
  for (int tn = 0; tn < 4; ++tn)
#pragma unroll
    for (int ks = 0; ks < 4; ++ks) {
      const float* gp = &Gg[(16 * tn + llo) * 256 + 128 * kg + 32 * ks + 8 * lhi];
      float4 q0 = *(const float4*)gp;
      float4 q1 = *(const float4*)(gp + 4);
      float f[8] = {q0.x, q0.y, q0.z, q0.w, q1.x, q1.y, q1.z, q1.w};
      split8(f, B1h[tn][ks], B1l[tn][ks]);
    }
  // ---- G fragments: MV2 B[k][n] = G[k][n] ----
  short8 B2h[4][2], B2l[4][2];
#pragma unroll
  for (int tn = 0; tn < 4; ++tn)
#pragma unroll
    for (int ks = 0; ks < 2; ++ks) {
      int col = 64 * wv + 16 * tn + llo;
      float f[8];
#pragma unroll
      for (int j = 0; j < 8; ++j) f[j] = Gg[(32 * ks + 8 * lhi + j) * 256 + col];
      split8(f, B2h[tn][ks], B2l[tn][ks]);
    }

  // ---- bounds, z, b' ----
  float lbr[4], ubr[4];
#pragma unroll
  for (int tn = 0; tn < 4; ++tn) {
    lbr[tn] = lb[64 * wv + 16 * tn + llo];
    ubr[tn] = ub[64 * wv + 16 * tn + llo];
  }
  float z[4][4][4];
#pragma unroll
  for (int tm = 0; tm < 4; ++tm)
#pragma unroll
    for (int tn = 0; tn < 4; ++tn)
#pragma unroll
      for (int reg = 0; reg < 4; ++reg)
        z[tm][tn][reg] = y0[(row_base + 16 * tm + 4 * lhi + reg) * 256 + 64 * wv + 16 * tn + llo];
  float bpr[16];
  {
    const float4* bp4 = (const float4*)&bpg[(row_base + (t >> 2)) * 64 + 16 * (t & 3)];
#pragma unroll
    for (int q = 0; q < 4; ++q) {
      float4 v = bp4[q];
      bpr[4 * q + 0] = v.x; bpr[4 * q + 1] = v.y; bpr[4 * q + 2] = v.z; bpr[4 * q + 3] = v.w;
    }
  }

  // ---- precomputed LDS addresses ----
  int waddr[4][4];  // phase-W store byte addr (+16384*tm)
  {
    int C0 = 64 * wv + llo, g0 = C0 >> 2, c3 = C0 & 3, R0 = 4 * lhi;
#pragma unroll
    for (int reg = 0; reg < 4; ++reg) {
      int hr = (R0 + reg) & 7;
#pragma unroll
      for (int tn = 0; tn < 4; ++tn)
        waddr[reg][tn] = 4 * (((R0 + reg) << 8) + ((((g0 + 4 * tn) ^ hr) << 2) | c3));
    }
  }
  int baseA0, baseA1;  // MV1 A-read byte bases (+16384*tm + 128*ks)
  {
    int rowA = 32 * mh + llo, hA = llo & 7, gA0 = 32 * kg + 2 * lhi;
    baseA0 = 4 * ((rowA << 8) + ((gA0 ^ hA) << 2));
    baseA1 = 4 * ((rowA << 8) + (((gA0 + 1) ^ hA) << 2));
  }
  const int pbase = kg * 4352 + (32 * mh + 4 * lhi) * 68 + llo;  // partial store f32 idx
  int baseR[2];  // MV2 A-read byte bases (+2048*tm)
  {
    int h2 = llo & 7;
#pragma unroll
    for (int ks = 0; ks < 2; ++ks)
      baseR[ks] = 4 * ((llo * 32) + (((4 * ks + lhi) ^ h2) << 2));
  }
  const int rrow = t >> 2;  // reduce-phase row

  for (int it = 0; it <= n_iter; ++it) {
    const bool last = (it == n_iter);

    // ---- phase W: w = 2p - z (p on final pass) -> LDS f32 swz ----
#pragma unroll
    for (int tm = 0; tm < 4; ++tm)
#pragma unroll
      for (int tn = 0; tn < 4; ++tn)
#pragma unroll
        for (int reg = 0; reg < 4; ++reg) {
          float zz = z[tm][tn][reg];
          float p = fminf(fmaxf(zz, lbr[tn]), ubr[tn]);
          float w = last ? p : fmaf(2.f, p, -zz);
          *(float*)((char*)wbuf + (waddr[reg][tn] + 16384 * tm)) = w;
        }
    __syncthreads();

    // ---- MV1: r_part = w @ G^T (wave = k-half x row-half) ----
    f32x4 acc1[2][4];
#pragma unroll
    for (int tm = 0; tm < 2; ++tm)
#pragma unroll
      for (int tn = 0; tn < 4; ++tn) acc1[tm][tn] = (f32x4){0.f, 0.f, 0.f, 0.f};
#pragma unroll
    for (int tm = 0; tm < 2; ++tm) {
      short8 Ah[4], Al[4];
#pragma unroll
      for (int ks = 0; ks < 4; ++ks) {
        float4 f0 = *(const float4*)((const char*)wbuf + (baseA0 + 16384 * tm + 128 * ks));
        float4 f1 = *(const float4*)((const char*)wbuf + (baseA1 + 16384 * tm + 128 * ks));
        float f[8] = {f0.x, f0.y, f0.z, f0.w, f1.x, f1.y, f1.z, f1.w};
        split8(f, Ah[ks], Al[ks]);
      }
#pragma unroll
      for (int tn = 0; tn < 4; ++tn)
#pragma unroll
        for (int ks = 0; ks < 4; ++ks) {
          acc1[tm][tn] = mfma16(Ah[ks], B1h[tn][ks], acc1[tm][tn]);
          acc1[tm][tn] = mfma16(Ah[ks], B1l[tn][ks], acc1[tm][tn]);
          acc1[tm][tn] = mfma16(Al[ks], B1h[tn][ks], acc1[tm][tn]);
        }
    }
#pragma unroll
    for (int tm = 0; tm < 2; ++tm)
#pragma unroll
      for (int tn = 0; tn < 4; ++tn)
#pragma unroll
        for (int reg = 0; reg < 4; ++reg)
          part[pbase + tm * 1088 + tn * 16 + reg * 68] = acc1[tm][tn][reg];
    __syncthreads();

    // ---- reduce partials, -b', split -> rs (bf16 hi/lo, swz) ----
    {
      const float* pp = &part[rrow * 68 + 16 * (t & 3)];
      float4 a0 = *(const float4*)(pp + 0), a1 = *(const float4*)(pp + 4);
      float4 a2 = *(const float4*)(pp + 8), a3 = *(const float4*)(pp + 12);
      float4 c0 = *(const float4*)(pp + 4352), c1 = *(const float4*)(pp + 4356);
      float4 c2 = *(const float4*)(pp + 4360), c3v = *(const float4*)(pp + 4364);
      float r[16];
      r[0] = a0.x + c0.x - bpr[0];  r[1] = a0.y + c0.y - bpr[1];
      r[2] = a0.z + c0.z - bpr[2];  r[3] = a0.w + c0.w - bpr[3];
      r[4] = a1.x + c1.x - bpr[4];  r[5] = a1.y + c1.y - bpr[5];
      r[6] = a1.z + c1.z - bpr[6];  r[7] = a1.w + c1.w - bpr[7];
      r[8] = a2.x + c2.x - bpr[8];  r[9] = a2.y + c2.y - bpr[9];
      r[10] = a2.z + c2.z - bpr[10]; r[11] = a2.w + c2.w - bpr[11];
      r[12] = a3.x + c3v.x - bpr[12]; r[13] = a3.y + c3v.y - bpr[13];
      r[14] = a3.z + c3v.z - bpr[14]; r[15] = a3.w + c3v.w - bpr[15];
      float rl[16];
#pragma unroll
      for (int i = 0; i < 16; ++i)
        rl[i] = r[i] - __uint_as_float(__float_as_uint(r[i]) & 0xFFFF0000u);
      int h = rrow & 7;
      int g0w = (2 * (t & 3)) ^ h, g1w = (2 * (t & 3) + 1) ^ h;
      uint4 uh0 = {pack_hi(r[0], r[1]), pack_hi(r[2], r[3]), pack_hi(r[4], r[5]), pack_hi(r[6], r[7])};
      uint4 uh1 = {pack_hi(r[8], r[9]), pack_hi(r[10], r[11]), pack_hi(r[12], r[13]), pack_hi(r[14], r[15])};
      uint4 ul0 = {pack_hi(rl[0], rl[1]), pack_hi(rl[2], rl[3]), pack_hi(rl[4], rl[5]), pack_hi(rl[6], rl[7])};
      uint4 ul1 = {pack_hi(rl[8], rl[9]), pack_hi(rl[10], rl[11]), pack_hi(rl[12], rl[13]), pack_hi(rl[14], rl[15])};
      *(uint4*)&rsh_[rrow * 32 + g0w * 4] = uh0;
      *(uint4*)&rsh_[rrow * 32 + g1w * 4] = uh1;
      *(uint4*)&rsl_[rrow * 32 + g0w * 4] = ul0;
      *(uint4*)&rsl_[rrow * 32 + g1w * 4] = ul1;
    }
    __syncthreads();

    // ---- MV2: corr = r @ G (wave = n-quarter) ----
    f32x4 acc2[4][4];
#pragma unroll
    for (int tm = 0; tm < 4; ++tm)
#pragma unroll
      for (int tn = 0; tn < 4; ++tn) acc2[tm][tn] = (f32x4){0.f, 0.f, 0.f, 0.f};
#pragma unroll
    for (int tm = 0; tm < 4; ++tm) {
      short8 Rh[2], Rl[2];
#pragma unroll
      for (int ks = 0; ks < 2; ++ks) {
        uint4 uh = *(const uint4*)((const char*)rsh_ + (baseR[ks] + 2048 * tm));
        uint4 ul = *(const uint4*)((const char*)rsl_ + (baseR[ks] + 2048 * tm));
        Rh[ks] = mk_short8(uh.x, uh.y, uh.z, uh.w);
        Rl[ks] = mk_short8(ul.x, ul.y, ul.z, ul.w);
      }
#pragma unroll
      for (int tn = 0; tn < 4; ++tn)
#pragma unroll
        for (int ks = 0; ks < 2; ++ks) {
          acc2[tm][tn] = mfma16(Rh[ks], B2h[tn][ks], acc2[tm][tn]);
          acc2[tm][tn] = mfma16(Rh[ks], B2l[tn][ks], acc2[tm][tn]);
          acc2[tm][tn] = mfma16(Rl[ks], B2h[tn][ks], acc2[tm][tn]);
        }
    }

    // ---- update / final store ----
    if (!last) {
#pragma unroll
      for (int tm = 0; tm < 4; ++tm)
#pragma unroll
        for (int tn = 0; tn < 4; ++tn)
#pragma unroll
          for (int reg = 0; reg < 4; ++reg) {
            float zz = z[tm][tn][reg];
            float p = fminf(fmaxf(zz, lbr[tn]), ubr[tn]);
            z[tm][tn][reg] = fmaf(1.7f, p - zz - acc2[tm][tn][reg], zz);
          }
    } else {
#pragma unroll
      for (int tm = 0; tm < 4; ++tm)
#pragma unroll
        for (int tn = 0; tn < 4; ++tn)
#pragma unroll
          for (int reg = 0; reg < 4; ++reg) {
            float zz = z[tm][tn][reg];
            float p = fminf(fmaxf(zz, lbr[tn]), ubr[tn]);
            out[(row_base + 16 * tm + 4 * lhi + reg) * 256 + 64 * wv + 16 * tn + llo] =
                p - acc2[tm][tn][reg];
          }
    }
  }
}

// ---------------------------------------------------------------------------
extern "C" void kernel_launch(void* const* d_in, const int* in_sizes, int n_in,
                              void* d_out, int out_size, void* d_ws, size_t ws_size,
                              hipStream_t stream) {
  (void)in_sizes; (void)n_in; (void)out_size; (void)ws_size;
  const float* x  = (const float*)d_in[0];
  const float* bM = (const float*)d_in[1];
  const float* W1 = (const float*)d_in[2];
  const float* b1 = (const float*)d_in[3];
  const float* W2 = (const float*)d_in[4];
  const float* b2 = (const float*)d_in[5];
  const float* W3 = (const float*)d_in[6];
  const float* b3 = (const float*)d_in[7];
  const float* A  = (const float*)d_in[8];
  const float* lb = (const float*)d_in[9];
  const float* ub = (const float*)d_in[10];
  const int* n_iter = (const int*)d_in[11];
  float* out = (float*)d_out;

  float* ws = (float*)d_ws;
  float* y  = ws;                       // 16384*256
  float* h1 = ws;                       // 16384*200 (overlays y; dead before y written)
  float* h2 = y + 16384 * 256;          // 16384*200
  float* bp = h2 + 16384 * 200;         // 16384*64
  float* G  = bp + 16384 * 64;          // 64*256
  float* L  = G + 64 * 256;             // 64*64

  hipLaunchKernelGGL(prep_kernel, dim3(1), dim3(256), 0, stream, A, G, L);
  hipLaunchKernelGGL(bprime_kernel, dim3(64), dim3(256), 0, stream, bM, L, bp);
  hipLaunchKernelGGL(gemm_kernel, dim3(256, 4), dim3(256), 0, stream, x,  W1, b1, h1, 16384, 200, 256, 1);
  hipLaunchKernelGGL(gemm_kernel, dim3(256, 4), dim3(256), 0, stream, h1, W2, b2, h2, 16384, 200, 200, 1);
  hipLaunchKernelGGL(gemm_kernel, dim3(256, 4), dim3(256), 0, stream, h2, W3, b3, y,  16384, 256, 200, 0);
  hipLaunchKernelGGL(iter_kernel, dim3(256), dim3(256), 0, stream, y, G, bp, lb, ub, n_iter, out);
}

// Round 3
// 702.959 us; speedup vs baseline: 3.5183x; 1.3437x over previous
//
#include <hip/hip_runtime.h>

// ---------------------------------------------------------------------------
// HardConstrainedMLP: 3-layer MLP -> 100 relaxed DR iterations -> P_eq(P_box)
//   AAT = A A^T + 1e-6 I = L L^T,  G = L^{-1}A (64x256),  b' = L^{-1} b_row
//   corr(w) = (w@G^T - b')@G ;  z += 1.7*(clip(z) - z - corr(2*clip(z)-z))
// R3: spill-free iter kernel. 512 blocks x 256 thr (32 rows/block, 2 blk/CU).
//   MV1: r^T = G @ w^T  (wave = k-quarter; G row-frags, 64 VGPR; f32 partials)
//   MV2: corr^T = G^T @ r^T (wave = d-quarter; G col-frags, 64 VGPR) -> output
//        lands exactly in z's C/D register layout; z-update + w-write fused.
// ---------------------------------------------------------------------------

typedef float f32x4 __attribute__((ext_vector_type(4)));
typedef unsigned u32x4 __attribute__((ext_vector_type(4)));
typedef short short8 __attribute__((ext_vector_type(8)));

__device__ __forceinline__ unsigned pack_hi(float a, float b) {
  // (bf16bits(b) << 16) | bf16bits(a)
  return __builtin_amdgcn_perm(__float_as_uint(b), __float_as_uint(a), 0x07060302u);
}
__device__ __forceinline__ unsigned perm_hh(unsigned a, unsigned b) {
  return __builtin_amdgcn_perm(b, a, 0x07060302u);  // (b.hi16<<16)|a.hi16
}
__device__ __forceinline__ unsigned perm_ll(unsigned a, unsigned b) {
  return __builtin_amdgcn_perm(b, a, 0x05040100u);  // (b.lo16<<16)|a.lo16
}
__device__ __forceinline__ short8 mk_short8(unsigned a, unsigned b, unsigned c, unsigned d) {
  union { unsigned u[4]; short8 v; } x;
  x.u[0] = a; x.u[1] = b; x.u[2] = c; x.u[3] = d;
  return x.v;
}
__device__ __forceinline__ void split8(const float* f, short8& hi, short8& lo) {
  float lof[8];
#pragma unroll
  for (int i = 0; i < 8; ++i)
    lof[i] = f[i] - __uint_as_float(__float_as_uint(f[i]) & 0xFFFF0000u);
  hi = mk_short8(pack_hi(f[0], f[1]), pack_hi(f[2], f[3]), pack_hi(f[4], f[5]), pack_hi(f[6], f[7]));
  lo = mk_short8(pack_hi(lof[0], lof[1]), pack_hi(lof[2], lof[3]), pack_hi(lof[4], lof[5]), pack_hi(lof[6], lof[7]));
}
__device__ __forceinline__ unsigned packword(float r) {
  float h = __uint_as_float(__float_as_uint(r) & 0xFFFF0000u);
  return pack_hi(r - h, r);  // low16 = bf16(lo), high16 = bf16(hi)
}
__device__ __forceinline__ f32x4 mfma16(short8 a, short8 b, f32x4 c) {
  return __builtin_amdgcn_mfma_f32_16x16x32_bf16(a, b, c, 0, 0, 0);
}

// ---------------- P1: AAT, Cholesky L, Linv, G = Linv @ A -------------------
__global__ __launch_bounds__(512) void prep_kernel(const float* __restrict__ A,
                                                   float* __restrict__ G_out,
                                                   float* __restrict__ LinvT) {
  __shared__ float As[64 * 260];
  __shared__ float T[64 * 65];
  __shared__ float Xi[64 * 65];  // Linv
  const int t = threadIdx.x;

  for (int q = 0; q < 8; ++q) {
    int f = 4 * (t + 512 * q);
    f32x4 v = *(const f32x4*)&A[f];
    int m = f >> 8, d = f & 255;
    As[m * 260 + d] = v[0]; As[m * 260 + d + 1] = v[1];
    As[m * 260 + d + 2] = v[2]; As[m * 260 + d + 3] = v[3];
  }
  __syncthreads();

  for (int q = 0; q < 8; ++q) {
    int f = t + 512 * q;
    int i = f >> 6, j = f & 63;
    float s = 0.f;
    for (int d = 0; d < 256; d += 4) {
      f32x4 xa = *(const f32x4*)&As[i * 260 + d];
      f32x4 xb = *(const f32x4*)&As[j * 260 + d];
      s += xa[0] * xb[0] + xa[1] * xb[1] + xa[2] * xb[2] + xa[3] * xb[3];
    }
    if (i == j) s += 1e-6f;
    T[i * 65 + j] = s;
  }
  __syncthreads();

  if (t < 64) {
    // wave-lockstep Cholesky (lower), no barriers needed within wave 0
    for (int j = 0; j < 64; ++j) {
      float dj = sqrtf(T[j * 65 + j]);
      float lij = 0.f;
      if (t == j) T[j * 65 + j] = dj;
      if (t > j) { lij = T[t * 65 + j] / dj; T[t * 65 + j] = lij; }
      for (int k = j + 1; k <= t; ++k)
        T[t * 65 + k] -= lij * T[k * 65 + j];
    }
    // Linv: lane t solves L x = e_t (column t), per-lane independent
    for (int i = 0; i < 64; ++i) {
      float s = (i == t) ? 1.f : 0.f;
      for (int j = t; j < i; ++j) s -= T[i * 65 + j] * Xi[j * 65 + t];
      Xi[i * 65 + t] = (i >= t) ? s / T[i * 65 + i] : 0.f;
    }
    for (int i = 0; i < 64; ++i) LinvT[t * 64 + i] = Xi[i * 65 + t];
  }
  __syncthreads();

  // G = Linv @ A : thread covers col d = t&255, i-range 32*(t>>8)..+32
  {
    int d = t & 255, i0 = (t >> 8) * 32;
    for (int c = 0; c < 4; ++c) {
      float acc[8] = {};
      for (int j = 0; j < 64; ++j) {
        float a = As[j * 260 + d];
#pragma unroll
        for (int u = 0; u < 8; ++u) acc[u] += Xi[(i0 + 8 * c + u) * 65 + j] * a;
      }
#pragma unroll
      for (int u = 0; u < 8; ++u) G_out[(i0 + 8 * c + u) * 256 + d] = acc[u];
    }
  }
}

// ---------------- MLP / bp: fp32 tiled GEMM, 64x128 tile, 2 blk/CU ---------
__global__ __launch_bounds__(256) void gemm64(const float* __restrict__ X,
                                              const float* __restrict__ W,
                                              const float* __restrict__ bias,
                                              float* __restrict__ Y,
                                              int N, int K, int relu) {
  __shared__ float Xs[8][68];
  __shared__ float Ws[8][132];
  const int t = threadIdx.x;
  const int row0 = blockIdx.x * 64, n0 = blockIdx.y * 128;
  const int ty = t >> 4, tx = t & 15;
  const int xr = t >> 2, xk = (t & 3) * 2;
  const int wk = t >> 5, wn = (t & 31) * 4;
  float acc[4][8] = {};
  for (int kc = 0; kc < K; kc += 8) {
    float2 xv = *(const float2*)&X[(size_t)(row0 + xr) * K + kc + xk];
    f32x4 wv4 = {0.f, 0.f, 0.f, 0.f};
    if (n0 + wn + 4 <= N) {
      wv4 = *(const f32x4*)&W[(size_t)(kc + wk) * N + n0 + wn];
    } else {
#pragma unroll
      for (int e = 0; e < 4; ++e)
        if (n0 + wn + e < N) wv4[e] = W[(size_t)(kc + wk) * N + n0 + wn + e];
    }
    __syncthreads();
    Xs[xk][xr] = xv.x;
    Xs[xk + 1][xr] = xv.y;
    *(f32x4*)&Ws[wk][wn] = wv4;
    __syncthreads();
#pragma unroll
    for (int k = 0; k < 8; ++k) {
      f32x4 a = *(const f32x4*)&Xs[k][ty * 4];
      f32x4 b0 = *(const f32x4*)&Ws[k][tx * 8];
      f32x4 b1 = *(const f32x4*)&Ws[k][tx * 8 + 4];
#pragma unroll
      for (int i = 0; i < 4; ++i) {
        acc[i][0] += a[i] * b0[0]; acc[i][1] += a[i] * b0[1];
        acc[i][2] += a[i] * b0[2]; acc[i][3] += a[i] * b0[3];
        acc[i][4] += a[i] * b1[0]; acc[i][5] += a[i] * b1[1];
        acc[i][6] += a[i] * b1[2]; acc[i][7] += a[i] * b1[3];
      }
    }
  }
#pragma unroll
  for (int i = 0; i < 4; ++i) {
    int row = row0 + ty * 4 + i;
#pragma unroll
    for (int jj = 0; jj < 2; ++jj) {
      int c0 = n0 + tx * 8 + jj * 4;
      if (c0 >= N) continue;
      f32x4 v;
#pragma unroll
      for (int e = 0; e < 4; ++e) {
        float bv = bias ? bias[min(c0 + e, N - 1)] : 0.f;
        v[e] = acc[i][4 * jj + e] + bv;
        if (relu) v[e] = fmaxf(v[e], 0.f);
      }
      if (c0 + 4 <= N) {
        *(f32x4*)&Y[(size_t)row * N + c0] = v;
      } else {
#pragma unroll
        for (int e = 0; e < 4; ++e)
          if (c0 + e < N) Y[(size_t)row * N + c0 + e] = v[e];
      }
    }
  }
}

// ---------------- ITER: fused 100x DR on MFMA, spill-free ------------------
// 512 blocks x 256 thr (4 waves), 32 rows/block -> 2 blocks/CU.
// z[td][tr] f32x4: row = R0+16tr+llo, d = 64wv+16td+4lhi+reg  (C/D layout)
__global__ __launch_bounds__(256, 2) void iter_kernel(const float* __restrict__ y0,
                                                      const float* __restrict__ Gg,
                                                      const float* __restrict__ bpg,
                                                      const float* __restrict__ lb,
                                                      const float* __restrict__ ub,
                                                      const int* __restrict__ n_iter_p,
                                                      float* __restrict__ out) {
  __shared__ __align__(16) float wbuf[32 * 256];     // w f32, granule-4 XOR swz
  __shared__ __align__(16) float part[4 * 32 * 68];  // MV1 partials [kq][row][m]
  __shared__ __align__(16) unsigned rs[32 * 68];     // r packed (hi16|lo16)

  const int t = threadIdx.x, wv = t >> 6, lane = t & 63;
  const int lhi = lane >> 4, llo = lane & 15;
  const int llo3 = llo & 7;
  const int R0 = blockIdx.x * 32;
  const int n_iter = n_iter_p[0];

  // swizzle bases: granule(row,d) = (d>>2) ^ (row&7); row&7 == llo&7 here
  const int X0 = (16 * wv + lhi) ^ llo3;      // w-write granule base (+4*td XOR)
  const int Y0 = (16 * wv + 2 * lhi) ^ llo3;  // MV1 read granule base (^8ks ^c)

  // ---- G frags: MV1 A-op = G row-slices: GA[tn][ks] = G[16tn+llo][64wv+32ks+8lhi+j]
  short8 GAh[4][2], GAl[4][2];
#pragma unroll
  for (int tn = 0; tn < 4; ++tn)
#pragma unroll
    for (int ks = 0; ks < 2; ++ks) {
      const float* gp = &Gg[(16 * tn + llo) * 256 + 64 * wv + 32 * ks + 8 * lhi];
      f32x4 q0 = *(const f32x4*)gp;
      f32x4 q1 = *(const f32x4*)(gp + 4);
      float f[8] = {q0[0], q0[1], q0[2], q0[3], q1[0], q1[1], q1[2], q1[3]};
      split8(f, GAh[tn][ks], GAl[tn][ks]);
    }
  // ---- MV2 A-op = G col-slices: GB[td][ks] = G[32ks+8lhi+j][64wv+16td+llo]
  short8 GBh[4][2], GBl[4][2];
#pragma unroll
  for (int td = 0; td < 4; ++td)
#pragma unroll
    for (int ks = 0; ks < 2; ++ks) {
      float f[8];
#pragma unroll
      for (int j = 0; j < 8; ++j)
        f[j] = Gg[(32 * ks + 8 * lhi + j) * 256 + 64 * wv + 16 * td + llo];
      split8(f, GBh[td][ks], GBl[td][ks]);
    }

  // ---- bounds / b' / z init ----
  f32x4 lbr[4], ubr[4];
#pragma unroll
  for (int td = 0; td < 4; ++td) {
    lbr[td] = *(const f32x4*)&lb[64 * wv + 16 * td + 4 * lhi];
    ubr[td] = *(const f32x4*)&ub[64 * wv + 16 * td + 4 * lhi];
  }
  const int rrow = t >> 3, m8 = (t & 7) << 3;  // reduce-phase mapping
  f32x4 bpr0 = *(const f32x4*)&bpg[(R0 + rrow) * 64 + m8];
  f32x4 bpr1 = *(const f32x4*)&bpg[(R0 + rrow) * 64 + m8 + 4];

  f32x4 z[4][2];
#pragma unroll
  for (int tr = 0; tr < 2; ++tr) {
    char* wrow = (char*)wbuf + ((16 * tr + llo) << 10);
#pragma unroll
    for (int td = 0; td < 4; ++td) {
      f32x4 v = *(const f32x4*)&y0[(R0 + 16 * tr + llo) * 256 + 64 * wv + 16 * td + 4 * lhi];
      z[td][tr] = v;
      f32x4 wq;
#pragma unroll
      for (int e = 0; e < 4; ++e) {
        float p = fminf(fmaxf(v[e], lbr[td][e]), ubr[td][e]);
        wq[e] = (n_iter == 0) ? p : fmaf(2.f, p, -v[e]);
      }
      *(f32x4*)(wrow + ((X0 ^ (td << 2)) << 4)) = wq;
    }
  }
  __syncthreads();

  for (int it = 0; it <= n_iter; ++it) {
    const bool last = (it == n_iter);
    const bool nextlast = (it == n_iter - 1);

    // ---- MV1: partial r^T = G @ w^T over this wave's k-quarter ----
#pragma unroll
    for (int tr = 0; tr < 2; ++tr) {
      f32x4 acc1[4];
#pragma unroll
      for (int tn = 0; tn < 4; ++tn) acc1[tn] = (f32x4){0.f, 0.f, 0.f, 0.f};
      const char* wrow = (const char*)wbuf + ((16 * tr + llo) << 10);
#pragma unroll
      for (int ks = 0; ks < 2; ++ks) {
        int g0 = Y0 ^ (ks << 3);
        f32x4 f0 = *(const f32x4*)(wrow + (g0 << 4));
        f32x4 f1 = *(const f32x4*)(wrow + ((g0 ^ 1) << 4));
        float f[8] = {f0[0], f0[1], f0[2], f0[3], f1[0], f1[1], f1[2], f1[3]};
        short8 Ah, Al;
        split8(f, Ah, Al);
#pragma unroll
        for (int tn = 0; tn < 4; ++tn) {
          acc1[tn] = mfma16(GAh[tn][ks], Ah, acc1[tn]);
          acc1[tn] = mfma16(GAh[tn][ks], Al, acc1[tn]);
          acc1[tn] = mfma16(GAl[tn][ks], Ah, acc1[tn]);
        }
      }
      float* pp = &part[wv * 2176 + (16 * tr + llo) * 68 + 4 * lhi];
#pragma unroll
      for (int tn = 0; tn < 4; ++tn) *(f32x4*)(pp + 16 * tn) = acc1[tn];
    }
    __syncthreads();

    // ---- reduce 4 k-partials, subtract b', split+pack to bf16 hi|lo ----
    {
      const float* pp = &part[rrow * 68 + m8];
      f32x4 s0 = *(const f32x4*)pp;
      f32x4 s1 = *(const f32x4*)(pp + 4);
      f32x4 q0 = *(const f32x4*)(pp + 2176), q1 = *(const f32x4*)(pp + 2180);
      s0 += q0; s1 += q1;
      q0 = *(const f32x4*)(pp + 4352); q1 = *(const f32x4*)(pp + 4356);
      s0 += q0; s1 += q1;
      q0 = *(const f32x4*)(pp + 6528); q1 = *(const f32x4*)(pp + 6532);
      s0 += q0; s1 += q1;
      s0 -= bpr0; s1 -= bpr1;
      u32x4 o0 = {packword(s0[0]), packword(s0[1]), packword(s0[2]), packword(s0[3])};
      u32x4 o1 = {packword(s1[0]), packword(s1[1]), packword(s1[2]), packword(s1[3])};
      *(u32x4*)&rs[rrow * 68 + m8] = o0;
      *(u32x4*)&rs[rrow * 68 + m8 + 4] = o1;
    }
    __syncthreads();

    // ---- MV2: corr^T = G^T @ r^T ; fold z-update + next-w / final store ----
#pragma unroll
    for (int tr = 0; tr < 2; ++tr) {
      short8 Rh[2], Rl[2];
#pragma unroll
      for (int ks = 0; ks < 2; ++ks) {
        const unsigned* rp = &rs[(16 * tr + llo) * 68 + 32 * ks + 8 * lhi];
        u32x4 u0 = *(const u32x4*)rp;
        u32x4 u1 = *(const u32x4*)(rp + 4);
        Rh[ks] = mk_short8(perm_hh(u0[0], u0[1]), perm_hh(u0[2], u0[3]),
                           perm_hh(u1[0], u1[1]), perm_hh(u1[2], u1[3]));
        Rl[ks] = mk_short8(perm_ll(u0[0], u0[1]), perm_ll(u0[2], u0[3]),
                           perm_ll(u1[0], u1[1]), perm_ll(u1[2], u1[3]));
      }
      char* wrow = (char*)wbuf + ((16 * tr + llo) << 10);
#pragma unroll
      for (int td = 0; td < 4; ++td) {
        f32x4 c = {0.f, 0.f, 0.f, 0.f};
#pragma unroll
        for (int ks = 0; ks < 2; ++ks) {
          c = mfma16(GBh[td][ks], Rh[ks], c);
          c = mfma16(GBh[td][ks], Rl[ks], c);
          c = mfma16(GBl[td][ks], Rh[ks], c);
        }
        f32x4 zz = z[td][tr];
        if (!last) {
          f32x4 zn, wq;
#pragma unroll
          for (int e = 0; e < 4; ++e) {
            float p = fminf(fmaxf(zz[e], lbr[td][e]), ubr[td][e]);
            zn[e] = fmaf(1.7f, p - zz[e] - c[e], zz[e]);
            float pn = fminf(fmaxf(zn[e], lbr[td][e]), ubr[td][e]);
            wq[e] = nextlast ? pn : fmaf(2.f, pn, -zn[e]);
          }
          z[td][tr] = zn;
          *(f32x4*)(wrow + ((X0 ^ (td << 2)) << 4)) = wq;
        } else {
          f32x4 o;
#pragma unroll
          for (int e = 0; e < 4; ++e) {
            float p = fminf(fmaxf(zz[e], lbr[td][e]), ubr[td][e]);
            o[e] = p - c[e];
          }
          *(f32x4*)&out[(R0 + 16 * tr + llo) * 256 + 64 * wv + 16 * td + 4 * lhi] = o;
        }
      }
    }
    __syncthreads();
  }
}

// ---------------------------------------------------------------------------
extern "C" void kernel_launch(void* const* d_in, const int* in_sizes, int n_in,
                              void* d_out, int out_size, void* d_ws, size_t ws_size,
                              hipStream_t stream) {
  (void)in_sizes; (void)n_in; (void)out_size; (void)ws_size;
  const float* x  = (const float*)d_in[0];
  const float* bM = (const float*)d_in[1];
  const float* W1 = (const float*)d_in[2];
  const float* b1 = (const float*)d_in[3];
  const float* W2 = (const float*)d_in[4];
  const float* b2 = (const float*)d_in[5];
  const float* W3 = (const float*)d_in[6];
  const float* b3 = (const float*)d_in[7];
  const float* A  = (const float*)d_in[8];
  const float* lb = (const float*)d_in[9];
  const float* ub = (const float*)d_in[10];
  const int* n_iter = (const int*)d_in[11];
  float* out = (float*)d_out;

  float* ws = (float*)d_ws;
  float* y     = ws;                    // 16384*256
  float* h1    = ws;                    // 16384*200 (overlays y; dead before y)
  float* h2    = y + 16384 * 256;       // 16384*200
  float* bp    = h2 + 16384 * 200;      // 16384*64
  float* G     = bp + 16384 * 64;       // 64*256
  float* LinvT = G + 64 * 256;          // 64*64

  hipLaunchKernelGGL(prep_kernel, dim3(1), dim3(512), 0, stream, A, G, LinvT);
  hipLaunchKernelGGL(gemm64, dim3(256, 1), dim3(256), 0, stream, bM, LinvT, (const float*)nullptr, bp, 64, 64, 0);
  hipLaunchKernelGGL(gemm64, dim3(256, 2), dim3(256), 0, stream, x,  W1, b1, h1, 200, 256, 1);
  hipLaunchKernelGGL(gemm64, dim3(256, 2), dim3(256), 0, stream, h1, W2, b2, h2, 200, 200, 1);
  hipLaunchKernelGGL(gemm64, dim3(256, 2), dim3(256), 0, stream, h2, W3, b3, y,  256, 200, 0);
  hipLaunchKernelGGL(iter_kernel, dim3(512), dim3(256), 0, stream, y, G, bp, lb, ub, n_iter, out);
}

// Round 4
// 692.768 us; speedup vs baseline: 3.5701x; 1.0147x over previous
//
#include <hip/hip_runtime.h>

// ---------------------------------------------------------------------------
// HardConstrainedMLP: 3-layer MLP -> 100 relaxed DR iterations -> P_eq(P_box)
//   AAT = A A^T + 1e-6 I = L L^T,  G = L^{-1}A (64x256),  b' = L^{-1} b_row
//   corr(w) = (w@G^T - b')@G ;  z += 1.7*(clip(z) - z - corr(2*clip(z)-z))
// R4: no-spill iter (waves_per_eu(2,2)); MV1 on 32x32x16 MFMA; r exchanged as
//     bf16 hi/lo planes; uniform tail branches; setprio around MFMA clusters.
// ---------------------------------------------------------------------------

typedef float f32x4 __attribute__((ext_vector_type(4)));
typedef float f32x16 __attribute__((ext_vector_type(16)));
typedef unsigned u32x4 __attribute__((ext_vector_type(4)));
typedef short short8 __attribute__((ext_vector_type(8)));

__device__ __forceinline__ unsigned pack_hi(float a, float b) {
  // (bf16bits(b) << 16) | bf16bits(a)
  return __builtin_amdgcn_perm(__float_as_uint(b), __float_as_uint(a), 0x07060302u);
}
__device__ __forceinline__ float trunch(float x) {
  return __uint_as_float(__float_as_uint(x) & 0xFFFF0000u);
}
__device__ __forceinline__ void split2x4(f32x4 a, f32x4 b, short8& hi, short8& lo) {
  union { unsigned u[4]; short8 v; } H, L;
  H.u[0] = pack_hi(a[0], a[1]); H.u[1] = pack_hi(a[2], a[3]);
  H.u[2] = pack_hi(b[0], b[1]); H.u[3] = pack_hi(b[2], b[3]);
  float l0 = a[0] - trunch(a[0]), l1 = a[1] - trunch(a[1]);
  float l2 = a[2] - trunch(a[2]), l3 = a[3] - trunch(a[3]);
  float l4 = b[0] - trunch(b[0]), l5 = b[1] - trunch(b[1]);
  float l6 = b[2] - trunch(b[2]), l7 = b[3] - trunch(b[3]);
  L.u[0] = pack_hi(l0, l1); L.u[1] = pack_hi(l2, l3);
  L.u[2] = pack_hi(l4, l5); L.u[3] = pack_hi(l6, l7);
  hi = H.v; lo = L.v;
}
__device__ __forceinline__ f32x4 mfma16(short8 a, short8 b, f32x4 c) {
  return __builtin_amdgcn_mfma_f32_16x16x32_bf16(a, b, c, 0, 0, 0);
}
__device__ __forceinline__ f32x16 mfma32(short8 a, short8 b, f32x16 c) {
  return __builtin_amdgcn_mfma_f32_32x32x16_bf16(a, b, c, 0, 0, 0);
}

// ---------------- P1: AAT, Cholesky L, Linv, G = Linv @ A -------------------
__global__ __launch_bounds__(512) void prep_kernel(const float* __restrict__ A,
                                                   float* __restrict__ G_out,
                                                   float* __restrict__ LinvT) {
  __shared__ float As[64 * 260];
  __shared__ float T[64 * 65];
  __shared__ float Xi[64 * 65];  // Linv
  const int t = threadIdx.x;

  for (int q = 0; q < 8; ++q) {
    int f = 4 * (t + 512 * q);
    f32x4 v = *(const f32x4*)&A[f];
    int m = f >> 8, d = f & 255;
    As[m * 260 + d] = v[0]; As[m * 260 + d + 1] = v[1];
    As[m * 260 + d + 2] = v[2]; As[m * 260 + d + 3] = v[3];
  }
  __syncthreads();

  for (int q = 0; q < 8; ++q) {
    int f = t + 512 * q;
    int i = f >> 6, j = f & 63;
    float s = 0.f;
    for (int d = 0; d < 256; d += 4) {
      f32x4 xa = *(const f32x4*)&As[i * 260 + d];
      f32x4 xb = *(const f32x4*)&As[j * 260 + d];
      s += xa[0] * xb[0] + xa[1] * xb[1] + xa[2] * xb[2] + xa[3] * xb[3];
    }
    if (i == j) s += 1e-6f;
    T[i * 65 + j] = s;
  }
  __syncthreads();

  if (t < 64) {
    for (int j = 0; j < 64; ++j) {
      float dj = sqrtf(T[j * 65 + j]);
      float lij = 0.f;
      if (t == j) T[j * 65 + j] = dj;
      if (t > j) { lij = T[t * 65 + j] / dj; T[t * 65 + j] = lij; }
      for (int k = j + 1; k <= t; ++k)
        T[t * 65 + k] -= lij * T[k * 65 + j];
    }
    for (int i = 0; i < 64; ++i) {
      float s = (i == t) ? 1.f : 0.f;
      for (int j = t; j < i; ++j) s -= T[i * 65 + j] * Xi[j * 65 + t];
      Xi[i * 65 + t] = (i >= t) ? s / T[i * 65 + i] : 0.f;
    }
    for (int i = 0; i < 64; ++i) LinvT[t * 64 + i] = Xi[i * 65 + t];
  }
  __syncthreads();

  {
    int d = t & 255, i0 = (t >> 8) * 32;
    for (int c = 0; c < 4; ++c) {
      float acc[8] = {};
      for (int j = 0; j < 64; ++j) {
        float a = As[j * 260 + d];
#pragma unroll
        for (int u = 0; u < 8; ++u) acc[u] += Xi[(i0 + 8 * c + u) * 65 + j] * a;
      }
#pragma unroll
      for (int u = 0; u < 8; ++u) G_out[(i0 + 8 * c + u) * 256 + d] = acc[u];
    }
  }
}

// ---------------- MLP / bp: fp32 tiled GEMM, 64x128 tile -------------------
__global__ __launch_bounds__(256) void gemm64(const float* __restrict__ X,
                                              const float* __restrict__ W,
                                              const float* __restrict__ bias,
                                              float* __restrict__ Y,
                                              int N, int K, int relu) {
  __shared__ float Xs[8][68];
  __shared__ float Ws[8][132];
  const int t = threadIdx.x;
  const int row0 = blockIdx.x * 64, n0 = blockIdx.y * 128;
  const int ty = t >> 4, tx = t & 15;
  const int xr = t >> 2, xk = (t & 3) * 2;
  const int wk = t >> 5, wn = (t & 31) * 4;
  float acc[4][8] = {};
  for (int kc = 0; kc < K; kc += 8) {
    float2 xv = *(const float2*)&X[(size_t)(row0 + xr) * K + kc + xk];
    f32x4 wv4 = {0.f, 0.f, 0.f, 0.f};
    if (n0 + wn + 4 <= N) {
      wv4 = *(const f32x4*)&W[(size_t)(kc + wk) * N + n0 + wn];
    } else {
#pragma unroll
      for (int e = 0; e < 4; ++e)
        if (n0 + wn + e < N) wv4[e] = W[(size_t)(kc + wk) * N + n0 + wn + e];
    }
    __syncthreads();
    Xs[xk][xr] = xv.x;
    Xs[xk + 1][xr] = xv.y;
    *(f32x4*)&Ws[wk][wn] = wv4;
    __syncthreads();
#pragma unroll
    for (int k = 0; k < 8; ++k) {
      f32x4 a = *(const f32x4*)&Xs[k][ty * 4];
      f32x4 b0 = *(const f32x4*)&Ws[k][tx * 8];
      f32x4 b1 = *(const f32x4*)&Ws[k][tx * 8 + 4];
#pragma unroll
      for (int i = 0; i < 4; ++i) {
        acc[i][0] += a[i] * b0[0]; acc[i][1] += a[i] * b0[1];
        acc[i][2] += a[i] * b0[2]; acc[i][3] += a[i] * b0[3];
        acc[i][4] += a[i] * b1[0]; acc[i][5] += a[i] * b1[1];
        acc[i][6] += a[i] * b1[2]; acc[i][7] += a[i] * b1[3];
      }
    }
  }
#pragma unroll
  for (int i = 0; i < 4; ++i) {
    int row = row0 + ty * 4 + i;
#pragma unroll
    for (int jj = 0; jj < 2; ++jj) {
      int c0 = n0 + tx * 8 + jj * 4;
      if (c0 >= N) continue;
      f32x4 v;
#pragma unroll
      for (int e = 0; e < 4; ++e) {
        float bv = bias ? bias[min(c0 + e, N - 1)] : 0.f;
        v[e] = acc[i][4 * jj + e] + bv;
        if (relu) v[e] = fmaxf(v[e], 0.f);
      }
      if (c0 + 4 <= N) {
        *(f32x4*)&Y[(size_t)row * N + c0] = v;
      } else {
#pragma unroll
        for (int e = 0; e < 4; ++e)
          if (c0 + e < N) Y[(size_t)row * N + c0 + e] = v[e];
      }
    }
  }
}

// ---------------- ITER: fused 100x DR on MFMA ------------------------------
// 512 blocks x 256 thr (4 waves), 32 rows/block, 2 blocks/CU.
// MV1 (32x32x16): partial r^T = G @ w^T, wave = k-quarter. A-frags (G rows)
//   in regs; B = w from LDS (f32, XOR-swz), split at consumer (read once).
// reduce: sum 4 partials - b', pack to bf16 hi/lo PLANES (consumer reads x4).
// MV2 (16x16x32): corr^T = G^T @ r^T, wave = d-quarter; output lands in z's
//   C/D layout; z-update + next-w-write fused; uniform tail branches.
__global__ __launch_bounds__(256) __attribute__((amdgpu_waves_per_eu(2, 2)))
void iter_kernel(const float* __restrict__ y0,
                 const float* __restrict__ Gg,
                 const float* __restrict__ bpg,
                 const float* __restrict__ lb,
                 const float* __restrict__ ub,
                 const int* __restrict__ n_iter_p,
                 float* __restrict__ out) {
  __shared__ __align__(16) float wbuf[32 * 256];     // 32 KB [row][d] f32, granule-XOR
  __shared__ __align__(16) float part[4 * 32 * 68];  // 34 KB [kq][row][68]
  __shared__ __align__(16) unsigned rs[2 * 32 * 32]; // 8 KB [plane][row][32u32], XOR

  const int t = threadIdx.x, wv = t >> 6, lane = t & 63;
  const int l31 = lane & 31, h = lane >> 5;   // 32x32 lane mapping
  const int lhi = lane >> 4, llo = lane & 15; // 16x16 lane mapping
  const int R0 = blockIdx.x * 32;
  const int n_iter = n_iter_p[0];

  // ---- MV1 A-frags (32x32): GA[mt][ks] = G[32mt + l31][64wv + 16ks + 8h + j]
  short8 GAh[2][4], GAl[2][4];
#pragma unroll
  for (int mt = 0; mt < 2; ++mt)
#pragma unroll
    for (int ks = 0; ks < 4; ++ks) {
      const float* gp = &Gg[(32 * mt + l31) * 256 + 64 * wv + 16 * ks + 8 * h];
      split2x4(*(const f32x4*)gp, *(const f32x4*)(gp + 4), GAh[mt][ks], GAl[mt][ks]);
    }
  // ---- MV2 A-frags (16x16): GB[td][ks2] = G[32ks2 + 8lhi + j][64wv + 16td + llo]
  short8 GBh[4][2], GBl[4][2];
#pragma unroll
  for (int td = 0; td < 4; ++td)
#pragma unroll
    for (int ks2 = 0; ks2 < 2; ++ks2) {
      f32x4 fa, fb;
#pragma unroll
      for (int j = 0; j < 4; ++j) {
        fa[j] = Gg[(32 * ks2 + 8 * lhi + j) * 256 + 64 * wv + 16 * td + llo];
        fb[j] = Gg[(32 * ks2 + 8 * lhi + 4 + j) * 256 + 64 * wv + 16 * td + llo];
      }
      split2x4(fa, fb, GBh[td][ks2], GBl[td][ks2]);
    }

  // ---- bounds (z layout) / b' (reduce layout) ----
  f32x4 lbr[4], ubr[4];
#pragma unroll
  for (int td = 0; td < 4; ++td) {
    lbr[td] = *(const f32x4*)&lb[64 * wv + 16 * td + 4 * lhi];
    ubr[td] = *(const f32x4*)&ub[64 * wv + 16 * td + 4 * lhi];
  }
  const int rrow = t >> 3, m8 = (t & 7) * 8;
  f32x4 bpr0 = *(const f32x4*)&bpg[(R0 + rrow) * 64 + m8];
  f32x4 bpr1 = *(const f32x4*)&bpg[(R0 + rrow) * 64 + m8 + 4];

  // ---- precomputed LDS byte addresses ----
  // w-write (producer): row = 16tr+llo, granule = (16wv+4td+lhi) ^ (row&7)
  int waddr[2][4];
  {
    int r3 = llo & 7;
#pragma unroll
    for (int tr = 0; tr < 2; ++tr)
#pragma unroll
      for (int td = 0; td < 4; ++td)
        waddr[tr][td] = (16 * tr + llo) * 1024 + 16 * (((16 * wv + 4 * td + lhi) ^ r3));
  }
  // MV1 w-read: row = l31, granule = (16wv + 4ks + 2h) ^ (l31&7); 2nd = ^16
  int raddr[4];
  {
    int r3 = l31 & 7;
#pragma unroll
    for (int ks = 0; ks < 4; ++ks)
      raddr[ks] = l31 * 1024 + 16 * ((16 * wv + 4 * ks + 2 * h) ^ r3);
  }
  // MV1 partial store base: part[wv][l31][4h + (imm: 8u+32mt)]
  const int pbase = ((wv * 32 + l31) * 68 + 4 * h) * 4;
  // reduce read base: part[kq(imm)][rrow][m8]
  const int prd = (rrow * 68 + m8) * 4;
  // rs write: [plane(imm)][rrow][16*((t&7)^(rrow&7))]
  const int rwr = rrow * 128 + 16 * ((t & 7) ^ (rrow & 7));
  // MV2 rs read: [plane(imm)][16tr+llo][16*((4ks2+lhi)^(llo&7))]
  int rrd[2][2];
  {
    int r3 = llo & 7;
#pragma unroll
    for (int tr = 0; tr < 2; ++tr)
#pragma unroll
      for (int ks2 = 0; ks2 < 2; ++ks2)
        rrd[tr][ks2] = (16 * tr + llo) * 128 + 16 * ((4 * ks2 + lhi) ^ r3);
  }

  // ---- z init + first w ----
  f32x4 z[4][2];
#pragma unroll
  for (int tr = 0; tr < 2; ++tr)
#pragma unroll
    for (int td = 0; td < 4; ++td) {
      f32x4 v = *(const f32x4*)&y0[(R0 + 16 * tr + llo) * 256 + 64 * wv + 16 * td + 4 * lhi];
      z[td][tr] = v;
      f32x4 wq;
#pragma unroll
      for (int e = 0; e < 4; ++e) {
        float p = fminf(fmaxf(v[e], lbr[td][e]), ubr[td][e]);
        wq[e] = (n_iter == 0) ? p : fmaf(2.f, p, -v[e]);
      }
      *(f32x4*)((char*)wbuf + waddr[tr][td]) = wq;
    }
  __syncthreads();

  for (int it = 0; it <= n_iter; ++it) {
    // ---- MV1: partial r^T = G @ w^T over this wave's k-quarter (32x32) ----
    f32x16 acc0 = {}, acc1 = {};
#pragma unroll
    for (int ks = 0; ks < 4; ++ks) {
      f32x4 f0 = *(const f32x4*)((const char*)wbuf + raddr[ks]);
      f32x4 f1 = *(const f32x4*)((const char*)wbuf + (raddr[ks] ^ 16));
      short8 Bh, Bl;
      split2x4(f0, f1, Bh, Bl);
      __builtin_amdgcn_s_setprio(1);
      acc0 = mfma32(GAh[0][ks], Bh, acc0);
      acc0 = mfma32(GAh[0][ks], Bl, acc0);
      acc0 = mfma32(GAl[0][ks], Bh, acc0);
      acc1 = mfma32(GAh[1][ks], Bh, acc1);
      acc1 = mfma32(GAh[1][ks], Bl, acc1);
      acc1 = mfma32(GAl[1][ks], Bh, acc1);
      __builtin_amdgcn_s_setprio(0);
    }
#pragma unroll
    for (int u = 0; u < 4; ++u) {
      f32x4 q0 = {acc0[4 * u], acc0[4 * u + 1], acc0[4 * u + 2], acc0[4 * u + 3]};
      f32x4 q1 = {acc1[4 * u], acc1[4 * u + 1], acc1[4 * u + 2], acc1[4 * u + 3]};
      *(f32x4*)((char*)part + (pbase + 32 * u)) = q0;
      *(f32x4*)((char*)part + (pbase + 32 * u + 128)) = q1;
    }
    __syncthreads();

    // ---- reduce 4 k-partials, -b', pack to bf16 hi/lo planes ----
    {
      const char* pb = (const char*)part + prd;
      f32x4 s0 = *(const f32x4*)pb;
      f32x4 s1 = *(const f32x4*)(pb + 16);
      s0 += *(const f32x4*)(pb + 8704);  s1 += *(const f32x4*)(pb + 8720);
      s0 += *(const f32x4*)(pb + 17408); s1 += *(const f32x4*)(pb + 17424);
      s0 += *(const f32x4*)(pb + 26112); s1 += *(const f32x4*)(pb + 26128);
      s0 -= bpr0; s1 -= bpr1;
      u32x4 hi4 = {pack_hi(s0[0], s0[1]), pack_hi(s0[2], s0[3]),
                   pack_hi(s1[0], s1[1]), pack_hi(s1[2], s1[3])};
      float l0 = s0[0] - trunch(s0[0]), l1 = s0[1] - trunch(s0[1]);
      float l2 = s0[2] - trunch(s0[2]), l3 = s0[3] - trunch(s0[3]);
      float l4 = s1[0] - trunch(s1[0]), l5 = s1[1] - trunch(s1[1]);
      float l6 = s1[2] - trunch(s1[2]), l7 = s1[3] - trunch(s1[3]);
      u32x4 lo4 = {pack_hi(l0, l1), pack_hi(l2, l3), pack_hi(l4, l5), pack_hi(l6, l7)};
      *(u32x4*)((char*)rs + rwr) = hi4;
      *(u32x4*)((char*)rs + (rwr + 4096)) = lo4;
    }
    __syncthreads();

    // ---- MV2: corr^T = G^T @ r^T (16x16), fused z-update / stores ----
#pragma unroll
    for (int tr = 0; tr < 2; ++tr) {
      short8 Rh[2], Rl[2];
#pragma unroll
      for (int ks2 = 0; ks2 < 2; ++ks2) {
        Rh[ks2] = *(const short8*)((const char*)rs + rrd[tr][ks2]);
        Rl[ks2] = *(const short8*)((const char*)rs + (rrd[tr][ks2] + 4096));
      }
      f32x4 c[4];
      __builtin_amdgcn_s_setprio(1);
#pragma unroll
      for (int td = 0; td < 4; ++td) {
        f32x4 cc = {};
        cc = mfma16(GBh[td][0], Rh[0], cc);
        cc = mfma16(GBh[td][0], Rl[0], cc);
        cc = mfma16(GBl[td][0], Rh[0], cc);
        cc = mfma16(GBh[td][1], Rh[1], cc);
        cc = mfma16(GBh[td][1], Rl[1], cc);
        cc = mfma16(GBl[td][1], Rh[1], cc);
        c[td] = cc;
      }
      __builtin_amdgcn_s_setprio(0);

      if (it < n_iter - 1) {
#pragma unroll
        for (int td = 0; td < 4; ++td) {
          f32x4 zz = z[td][tr], zn, wq;
#pragma unroll
          for (int e = 0; e < 4; ++e) {
            float p = fminf(fmaxf(zz[e], lbr[td][e]), ubr[td][e]);
            zn[e] = fmaf(1.7f, p - zz[e] - c[td][e], zz[e]);
            float pn = fminf(fmaxf(zn[e], lbr[td][e]), ubr[td][e]);
            wq[e] = fmaf(2.f, pn, -zn[e]);
          }
          z[td][tr] = zn;
          *(f32x4*)((char*)wbuf + waddr[tr][td]) = wq;
        }
      } else if (it == n_iter - 1) {
#pragma unroll
        for (int td = 0; td < 4; ++td) {
          f32x4 zz = z[td][tr], zn, wq;
#pragma unroll
          for (int e = 0; e < 4; ++e) {
            float p = fminf(fmaxf(zz[e], lbr[td][e]), ubr[td][e]);
            zn[e] = fmaf(1.7f, p - zz[e] - c[td][e], zz[e]);
            wq[e] = fminf(fmaxf(zn[e], lbr[td][e]), ubr[td][e]);  // w = p on final pass
          }
          z[td][tr] = zn;
          *(f32x4*)((char*)wbuf + waddr[tr][td]) = wq;
        }
      } else {
#pragma unroll
        for (int td = 0; td < 4; ++td) {
          f32x4 zz = z[td][tr], o;
#pragma unroll
          for (int e = 0; e < 4; ++e) {
            float p = fminf(fmaxf(zz[e], lbr[td][e]), ubr[td][e]);
            o[e] = p - c[td][e];
          }
          *(f32x4*)&out[(R0 + 16 * tr + llo) * 256 + 64 * wv + 16 * td + 4 * lhi] = o;
        }
      }
    }
    __syncthreads();
  }
}

// ---------------------------------------------------------------------------
extern "C" void kernel_launch(void* const* d_in, const int* in_sizes, int n_in,
                              void* d_out, int out_size, void* d_ws, size_t ws_size,
                              hipStream_t stream) {
  (void)in_sizes; (void)n_in; (void)out_size; (void)ws_size;
  const float* x  = (const float*)d_in[0];
  const float* bM = (const float*)d_in[1];
  const float* W1 = (const float*)d_in[2];
  const float* b1 = (const float*)d_in[3];
  const float* W2 = (const float*)d_in[4];
  const float* b2 = (const float*)d_in[5];
  const float* W3 = (const float*)d_in[6];
  const float* b3 = (const float*)d_in[7];
  const float* A  = (const float*)d_in[8];
  const float* lb = (const float*)d_in[9];
  const float* ub = (const float*)d_in[10];
  const int* n_iter = (const int*)d_in[11];
  float* out = (float*)d_out;

  float* ws = (float*)d_ws;
  float* y     = ws;                    // 16384*256
  float* h1    = ws;                    // 16384*200 (overlays y; dead before y)
  float* h2    = y + 16384 * 256;       // 16384*200
  float* bp    = h2 + 16384 * 200;      // 16384*64
  float* G     = bp + 16384 * 64;       // 64*256
  float* LinvT = G + 64 * 256;          // 64*64

  hipLaunchKernelGGL(prep_kernel, dim3(1), dim3(512), 0, stream, A, G, LinvT);
  hipLaunchKernelGGL(gemm64, dim3(256, 1), dim3(256), 0, stream, bM, LinvT, (const float*)nullptr, bp, 64, 64, 0);
  hipLaunchKernelGGL(gemm64, dim3(256, 2), dim3(256), 0, stream, x,  W1, b1, h1, 200, 256, 1);
  hipLaunchKernelGGL(gemm64, dim3(256, 2), dim3(256), 0, stream, h1, W2, b2, h2, 200, 200, 1);
  hipLaunchKernelGGL(gemm64, dim3(256, 2), dim3(256), 0, stream, h2, W3, b3, y,  256, 200, 0);
  hipLaunchKernelGGL(iter_kernel, dim3(512), dim3(256), 0, stream, y, G, bp, lb, ub, n_iter, out);
}